// Round 1
// baseline (816.287 us; speedup 1.0000x reference)
//
#include <hip/hip_runtime.h>

typedef unsigned short u16;
typedef unsigned int u32;
typedef unsigned long long u64;
typedef __bf16 bf16_t;
typedef bf16_t bf16x8 __attribute__((ext_vector_type(8)));
typedef float f32x4 __attribute__((ext_vector_type(4)));

typedef __attribute__((address_space(3))) u32 lds32_t;
typedef __attribute__((address_space(1))) u32 glb32_t;

#define DEV static __device__ __forceinline__

DEV f32x4 mfma16(bf16x8 a, bf16x8 b, f32x4 c) {
  return __builtin_amdgcn_mfma_f32_16x16x32_bf16(a, b, c, 0, 0, 0);
}

DEV u16 f2bf(float f) {  // RNE f32->bf16
  u32 u = __builtin_bit_cast(u32, f);
  u = (u + 0x7fffu + ((u >> 16) & 1u)) >> 16;
  return (u16)u;
}

// ===================== pack X: [4096][2048] bf16 = [zr | zi] =====================
__global__ __launch_bounds__(256) void pack_x(const float* __restrict__ zr,
                                              const float* __restrict__ zi,
                                              u16* __restrict__ X) {
  int idx = (blockIdx.x * 256 + threadIdx.x) * 4;
  int m = idx >> 11;
  int k = idx & 2047;
  const float* s = (k < 1024) ? (zr + m * 1024 + k) : (zi + m * 1024 + (k - 1024));
  f32x4 v = *(const f32x4*)s;
  u16* o = X + idx;
  o[0] = f2bf(v[0]); o[1] = f2bf(v[1]); o[2] = f2bf(v[2]); o[3] = f2bf(v[3]);
}

// ===================== pack weights into B^T layout [J][2048] bf16 =====================
// MODE 0: J=6144 QKV combined.  col j: section=j>>11 (q,k,v); head h=(j&2047)>>7;
//   within-head t=(j&127): t<64 real (f=h*64+t), t>=64 imag.
//   B^T[j][k] real: k<1024 ? wr[k][f] : -wi[k-1024][f];  imag: k<1024 ? wi[k][f] : wr[k-1024][f]
// MODE 1: J=2048 output projection. k indexes O' feature (h*128 + t), j output col (yr|yi).
template <int MODE>
__global__ __launch_bounds__(256) void pack_w(const float* __restrict__ w0r, const float* __restrict__ w0i,
                                              const float* __restrict__ w1r, const float* __restrict__ w1i,
                                              const float* __restrict__ w2r, const float* __restrict__ w2i,
                                              u16* __restrict__ out) {
  __shared__ u16 tile[64][68];
  int t = threadIdx.x;
  int j0 = blockIdx.x * 64;
  int k0 = blockIdx.y * 64;
  const float* src;
  float sign = 1.0f;
  int f0, r0;
  if (MODE == 0) {
    int section = j0 >> 11;
    int jj = j0 & 2047;
    int h = jj >> 7;
    bool real = ((jj & 127) < 64);
    f0 = h * 64;
    const float* wr = (section == 0) ? w0r : ((section == 1) ? w1r : w2r);
    const float* wi = (section == 0) ? w0i : ((section == 1) ? w1i : w2i);
    bool lowk = (k0 < 1024);
    r0 = lowk ? k0 : (k0 - 1024);
    if (real) { src = lowk ? wr : wi; sign = lowk ? 1.0f : -1.0f; }
    else      { src = lowk ? wi : wr; sign = 1.0f; }
  } else {
    int h = k0 >> 7;
    bool treal = ((k0 & 127) < 64);
    r0 = h * 64;
    bool lowj = (j0 < 1024);
    f0 = lowj ? j0 : (j0 - 1024);
    if (treal) { src = lowj ? w0r : w0i; sign = 1.0f; }
    else       { src = lowj ? w0i : w0r; sign = lowj ? -1.0f : 1.0f; }
  }
#pragma unroll
  for (int it = 0; it < 4; ++it) {
    int dk = it * 16 + (t >> 4);
    int df = (t & 15) * 4;
    f32x4 v = *(const f32x4*)(src + (size_t)(r0 + dk) * 1024 + f0 + df);
    u64 w = (u64)f2bf(sign * v[0]) | ((u64)f2bf(sign * v[1]) << 16) |
            ((u64)f2bf(sign * v[2]) << 32) | ((u64)f2bf(sign * v[3]) << 48);
    *(u64*)&tile[dk][df] = w;
  }
  __syncthreads();
#pragma unroll
  for (int it = 0; it < 4; ++it) {
    int df = it * 16 + (t >> 4);
    int dk0 = (t & 15) * 4;
    u64 w = (u64)tile[dk0][df] | ((u64)tile[dk0 + 1][df] << 16) |
            ((u64)tile[dk0 + 2][df] << 32) | ((u64)tile[dk0 + 3][df] << 48);
    *(u64*)(out + (size_t)(j0 + df) * 2048 + k0 + dk0) = w;
  }
}

// ===================== V transpose: C1 V-section -> VT[bh][d(128)][s(2048)] =====================
__global__ __launch_bounds__(256) void vtrans(const u16* __restrict__ C1, u16* __restrict__ VT) {
  __shared__ u16 tile[64][72];
  int t = threadIdx.x;
  int s0 = blockIdx.x * 64;
  int bh = blockIdx.y >> 1;
  int d0 = (blockIdx.y & 1) * 64;
  int b = bh >> 4, h = bh & 15;
  const u16* src = C1 + (size_t)(b * 2048 + s0) * 6144 + 4096 + h * 128 + d0;
#pragma unroll
  for (int it = 0; it < 2; ++it) {
    int ss = it * 32 + (t >> 3);
    int dd = (t & 7) * 8;
    uint4 v = *(const uint4*)(src + (size_t)ss * 6144 + dd);
    *(uint4*)&tile[ss][dd] = v;
  }
  __syncthreads();
#pragma unroll
  for (int it = 0; it < 2; ++it) {
    int dd = it * 32 + (t >> 3);
    int ss0 = (t & 7) * 8;
    union { u16 q[8]; uint4 v; } u;
#pragma unroll
    for (int i = 0; i < 8; ++i) u.q[i] = tile[ss0 + i][dd];
    *(uint4*)(VT + (size_t)(bh * 128 + d0 + dd) * 2048 + s0 + ss0) = u.v;
  }
}

// ===================== GEMM: C[M][N] = A[M][2048] @ Bt[N][2048]^T =====================
// 128x128 tile, BK=64, 4 waves (2x2), double-buffered LDS, global_load_lds w=16,
// XOR swizzle (linear LDS dest + pre-swizzled global source + swizzled ds_read).
// MODE 0: bf16 out, ld 6144 (C1).  MODE 1: fp32 out split into yr/yi halves of d_out.
template <int MODE>
__global__ __launch_bounds__(256, 2) void gemm_bt(const u16* __restrict__ A,
                                                  const u16* __restrict__ Bt,
                                                  void* __restrict__ Cout) {
  const int K = 2048;
  __shared__ u16 lds[2][2][8192];  // [dbuf][A,B][128*64]
  int tid = threadIdx.x;
  int lane = tid & 63;
  int c = lane & 15, g = lane >> 4;
  int wid = tid >> 6;
  int wr = wid >> 1, wc = wid & 1;
  size_t m0 = (size_t)blockIdx.y * 128;
  size_t n0 = (size_t)blockIdx.x * 128;
  const u16* Asrc = A + m0 * K;
  const u16* Bsrc = Bt + n0 * K;

  f32x4 acc[4][4];
#pragma unroll
  for (int i = 0; i < 4; ++i)
#pragma unroll
    for (int j = 0; j < 4; ++j) acc[i][j] = f32x4{0.f, 0.f, 0.f, 0.f};

  auto stage = [&](int buf, int kt) {
#pragma unroll
    for (int i = 0; i < 4; ++i) {
      int p = i * 4096 + tid * 16;             // physical byte offset in 16KB tile
      int row = p >> 7;                        // row stride 128B (64 bf16)
      int inner = (p & 127) ^ ((row & 7) << 4);  // logical byte-in-row
      int col = (kt * 128 + inner) >> 1;       // global k offset (shorts)
      __builtin_amdgcn_global_load_lds((glb32_t*)(Asrc + (size_t)row * K + col),
                                       (lds32_t*)(&lds[buf][0][p >> 1]), 16, 0, 0);
      __builtin_amdgcn_global_load_lds((glb32_t*)(Bsrc + (size_t)row * K + col),
                                       (lds32_t*)(&lds[buf][1][p >> 1]), 16, 0, 0);
    }
  };

  stage(0, 0);
  asm volatile("s_waitcnt vmcnt(0)" ::: "memory");
  __syncthreads();
  int cur = 0;
  for (int kt = 0; kt < 32; ++kt) {
    if (kt + 1 < 32) stage(cur ^ 1, kt + 1);
    const u16* Ab = &lds[cur][0][0];
    const u16* Bb = &lds[cur][1][0];
#pragma unroll
    for (int kk = 0; kk < 2; ++kk) {
      bf16x8 af[4], bfr[4];
#pragma unroll
      for (int i = 0; i < 4; ++i) {
        int rowA = wr * 64 + i * 16 + c;
        int offA = rowA * 128 + ((kk * 64 + g * 16) ^ ((rowA & 7) << 4));
        af[i] = *(const bf16x8*)(Ab + (offA >> 1));
        int rowB = wc * 64 + i * 16 + c;
        int offB = rowB * 128 + ((kk * 64 + g * 16) ^ ((rowB & 7) << 4));
        bfr[i] = *(const bf16x8*)(Bb + (offB >> 1));
      }
#pragma unroll
      for (int i = 0; i < 4; ++i)
#pragma unroll
        for (int j = 0; j < 4; ++j) acc[i][j] = mfma16(af[i], bfr[j], acc[i][j]);
    }
    __syncthreads();
    cur ^= 1;
  }

  if (MODE == 0) {
    u16* C = (u16*)Cout;
#pragma unroll
    for (int i = 0; i < 4; ++i)
#pragma unroll
      for (int j = 0; j < 4; ++j) {
        size_t row = m0 + wr * 64 + i * 16 + g * 4;
        size_t col = n0 + wc * 64 + j * 16 + c;
#pragma unroll
        for (int r = 0; r < 4; ++r) C[(row + r) * 6144 + col] = f2bf(acc[i][j][r]);
      }
  } else {
    float* Y = (float*)Cout;
#pragma unroll
    for (int i = 0; i < 4; ++i)
#pragma unroll
      for (int j = 0; j < 4; ++j) {
        size_t row = m0 + wr * 64 + i * 16 + g * 4;
        int col = (int)(n0 + wc * 64 + j * 16 + c);
        float* base = (col < 1024) ? (Y + col) : (Y + 4194304 + (col - 1024));
#pragma unroll
        for (int r = 0; r < 4; ++r) base[(row + r) * 1024] = acc[i][j][r];
      }
  }
}

// ===================== Flash attention, head_dim 128 = [real|imag] =====================
// 1 wave per block, 16 q-rows; KV tile 32. K frags from global (L2), V from VT (pre-transposed).
__global__ __launch_bounds__(64) void attn_fwd(const u16* __restrict__ C1,
                                               const u16* __restrict__ VT,
                                               u16* __restrict__ O) {
  __shared__ u16 P[16 * 40];  // P^T staging, row stride 40 (80B, 16B-aligned rows)
  int lane = threadIdx.x;
  int c = lane & 15, g = lane >> 4;
  int qt = blockIdx.x;
  int bh = blockIdx.y;
  int b = bh >> 4, h = bh & 15;
  const size_t LDC = 6144;
  const u16* Qb = C1 + (size_t)(b * 2048 + qt * 16) * LDC + h * 128;
  const u16* Kb = C1 + (size_t)(b * 2048) * LDC + 2048 + h * 128;
  const u16* Vb = VT + (size_t)bh * 128 * 2048;

  bf16x8 qf[4];
#pragma unroll
  for (int kk = 0; kk < 4; ++kk)
    qf[kk] = *(const bf16x8*)(Qb + (size_t)c * LDC + kk * 32 + g * 8);

  float mrun[4] = {-1e30f, -1e30f, -1e30f, -1e30f};
  float lrun[4] = {0.f, 0.f, 0.f, 0.f};
  f32x4 o[8];
#pragma unroll
  for (int nt = 0; nt < 8; ++nt) o[nt] = f32x4{0.f, 0.f, 0.f, 0.f};

  const float SC = 0.125f * 1.44269504f;  // SCALE * log2(e)

  for (int kv = 0; kv < 2048; kv += 32) {
    f32x4 s0 = f32x4{0.f, 0.f, 0.f, 0.f};
    f32x4 s1 = f32x4{0.f, 0.f, 0.f, 0.f};
#pragma unroll
    for (int kk = 0; kk < 4; ++kk) {
      bf16x8 kf0 = *(const bf16x8*)(Kb + (size_t)(kv + c) * LDC + kk * 32 + g * 8);
      bf16x8 kf1 = *(const bf16x8*)(Kb + (size_t)(kv + 16 + c) * LDC + kk * 32 + g * 8);
      s0 = mfma16(qf[kk], kf0, s0);
      s1 = mfma16(qf[kk], kf1, s1);
    }
    asm volatile("" ::: "memory");  // order prev pa-read before P overwrite
#pragma unroll
    for (int r = 0; r < 4; ++r) {
      float a = s0[r] * SC, bb = s1[r] * SC;
      float mx = fmaxf(a, bb);
      mx = fmaxf(mx, __shfl_xor(mx, 1));
      mx = fmaxf(mx, __shfl_xor(mx, 2));
      mx = fmaxf(mx, __shfl_xor(mx, 4));
      mx = fmaxf(mx, __shfl_xor(mx, 8));
      float mn = fmaxf(mrun[r], mx);
      float al = exp2f(mrun[r] - mn);
      mrun[r] = mn;
      float p0 = exp2f(a - mn);
      float p1 = exp2f(bb - mn);
      float sm = p0 + p1;
      sm += __shfl_xor(sm, 1);
      sm += __shfl_xor(sm, 2);
      sm += __shfl_xor(sm, 4);
      sm += __shfl_xor(sm, 8);
      lrun[r] = lrun[r] * al + sm;
#pragma unroll
      for (int nt = 0; nt < 8; ++nt) o[nt][r] *= al;
      P[(4 * g + r) * 40 + c] = f2bf(p0);
      P[(4 * g + r) * 40 + 16 + c] = f2bf(p1);
    }
    asm volatile("" ::: "memory");  // order P writes before pa read (wave-internal exchange)
    bf16x8 pa = *(const bf16x8*)(&P[c * 40 + g * 8]);
#pragma unroll
    for (int nt = 0; nt < 8; ++nt) {
      bf16x8 vf = *(const bf16x8*)(Vb + (size_t)(nt * 16 + c) * 2048 + kv + g * 8);
      o[nt] = mfma16(pa, vf, o[nt]);
    }
  }

  float inv[4];
#pragma unroll
  for (int r = 0; r < 4; ++r) inv[r] = 1.0f / lrun[r];
#pragma unroll
  for (int nt = 0; nt < 8; ++nt)
#pragma unroll
    for (int r = 0; r < 4; ++r) {
      size_t row = (size_t)(b * 2048 + qt * 16 + 4 * g + r);
      O[row * 2048 + h * 128 + nt * 16 + c] = f2bf(o[nt][r] * inv[r]);
    }
}

// ===================== launch =====================
extern "C" void kernel_launch(void* const* d_in, const int* in_sizes, int n_in,
                              void* d_out, int out_size, void* d_ws, size_t ws_size,
                              hipStream_t stream) {
  const float* zr   = (const float*)d_in[0];
  const float* zi   = (const float*)d_in[1];
  const float* wq_r = (const float*)d_in[2];
  const float* wq_i = (const float*)d_in[3];
  const float* wk_r = (const float*)d_in[4];
  const float* wk_i = (const float*)d_in[5];
  const float* wv_r = (const float*)d_in[6];
  const float* wv_i = (const float*)d_in[7];
  const float* wo_r = (const float*)d_in[8];
  const float* wo_i = (const float*)d_in[9];

  if (ws_size < (size_t)134217728) return;  // need 128 MiB scratch

  char* ws = (char*)d_ws;
  u16* X    = (u16*)(ws + 0);          //  16 MiB: [4096][2048]
  u16* Wqkv = (u16*)(ws + 16777216);   //  24 MiB: [6144][2048]
  u16* C1   = (u16*)(ws + 41943040);   //  48 MiB: [4096][6144] = [Q|K|V] head-interleaved
  u16* VT   = (u16*)(ws + 92274688);   //  16 MiB: [32][128][2048]
  u16* O    = (u16*)(ws + 109051904);  //  16 MiB: [4096][2048]
  u16* Wo   = (u16*)(ws + 125829120);  //   8 MiB: [2048][2048]

  pack_x<<<8192, 256, 0, stream>>>(zr, zi, X);
  pack_w<0><<<dim3(96, 32), 256, 0, stream>>>(wq_r, wq_i, wk_r, wk_i, wv_r, wv_i, Wqkv);
  pack_w<1><<<dim3(32, 32), 256, 0, stream>>>(wo_r, wo_i, wo_r, wo_i, wo_r, wo_i, Wo);
  gemm_bt<0><<<dim3(48, 32), 256, 0, stream>>>(X, Wqkv, C1);
  vtrans<<<dim3(32, 64), 256, 0, stream>>>(C1, VT);
  attn_fwd<<<dim3(128, 32), 64, 0, stream>>>(C1, VT, O);
  gemm_bt<1><<<dim3(16, 32), 256, 0, stream>>>(O, Wo, (float*)d_out);
}

// Round 2
// 440.577 us; speedup vs baseline: 1.8528x; 1.8528x over previous
//
#include <hip/hip_runtime.h>

typedef unsigned short u16;
typedef unsigned int u32;
typedef unsigned long long u64;
typedef __bf16 bf16_t;
typedef bf16_t bf16x8 __attribute__((ext_vector_type(8)));
typedef float f32x4 __attribute__((ext_vector_type(4)));

typedef __attribute__((address_space(3))) u32 lds32_t;
typedef __attribute__((address_space(1))) u32 glb32_t;

#define DEV static __device__ __forceinline__

DEV f32x4 mfma16(bf16x8 a, bf16x8 b, f32x4 c) {
  return __builtin_amdgcn_mfma_f32_16x16x32_bf16(a, b, c, 0, 0, 0);
}

DEV u16 f2bf(float f) {  // RNE f32->bf16
  u32 u = __builtin_bit_cast(u32, f);
  u = (u + 0x7fffu + ((u >> 16) & 1u)) >> 16;
  return (u16)u;
}

DEV u32 pk2(float a, float b) { return (u32)f2bf(a) | ((u32)f2bf(b) << 16); }

// ===================== pack X: [4096][2048] bf16 = [zr | zi] =====================
__global__ __launch_bounds__(256) void pack_x(const float* __restrict__ zr,
                                              const float* __restrict__ zi,
                                              u16* __restrict__ X) {
  int idx = (blockIdx.x * 256 + threadIdx.x) * 4;
  int m = idx >> 11;
  int k = idx & 2047;
  const float* s = (k < 1024) ? (zr + m * 1024 + k) : (zi + m * 1024 + (k - 1024));
  f32x4 v = *(const f32x4*)s;
  u16* o = X + idx;
  o[0] = f2bf(v[0]); o[1] = f2bf(v[1]); o[2] = f2bf(v[2]); o[3] = f2bf(v[3]);
}

// ===================== pack weights into B^T layout [J][2048] bf16 =====================
template <int MODE>
__global__ __launch_bounds__(256) void pack_w(const float* __restrict__ w0r, const float* __restrict__ w0i,
                                              const float* __restrict__ w1r, const float* __restrict__ w1i,
                                              const float* __restrict__ w2r, const float* __restrict__ w2i,
                                              u16* __restrict__ out) {
  __shared__ u16 tile[64][68];
  int t = threadIdx.x;
  int j0 = blockIdx.x * 64;
  int k0 = blockIdx.y * 64;
  const float* src;
  float sign = 1.0f;
  int f0, r0;
  if (MODE == 0) {
    int section = j0 >> 11;
    int jj = j0 & 2047;
    int h = jj >> 7;
    bool real = ((jj & 127) < 64);
    f0 = h * 64;
    const float* wr = (section == 0) ? w0r : ((section == 1) ? w1r : w2r);
    const float* wi = (section == 0) ? w0i : ((section == 1) ? w1i : w2i);
    bool lowk = (k0 < 1024);
    r0 = lowk ? k0 : (k0 - 1024);
    if (real) { src = lowk ? wr : wi; sign = lowk ? 1.0f : -1.0f; }
    else      { src = lowk ? wi : wr; sign = 1.0f; }
  } else {
    int h = k0 >> 7;
    bool treal = ((k0 & 127) < 64);
    r0 = h * 64;
    bool lowj = (j0 < 1024);
    f0 = lowj ? j0 : (j0 - 1024);
    if (treal) { src = lowj ? w0r : w0i; sign = 1.0f; }
    else       { src = lowj ? w0i : w0r; sign = lowj ? -1.0f : 1.0f; }
  }
#pragma unroll
  for (int it = 0; it < 4; ++it) {
    int dk = it * 16 + (t >> 4);
    int df = (t & 15) * 4;
    f32x4 v = *(const f32x4*)(src + (size_t)(r0 + dk) * 1024 + f0 + df);
    u64 w = (u64)f2bf(sign * v[0]) | ((u64)f2bf(sign * v[1]) << 16) |
            ((u64)f2bf(sign * v[2]) << 32) | ((u64)f2bf(sign * v[3]) << 48);
    *(u64*)&tile[dk][df] = w;
  }
  __syncthreads();
#pragma unroll
  for (int it = 0; it < 4; ++it) {
    int df = it * 16 + (t >> 4);
    int dk0 = (t & 15) * 4;
    u64 w = (u64)tile[dk0][df] | ((u64)tile[dk0 + 1][df] << 16) |
            ((u64)tile[dk0 + 2][df] << 32) | ((u64)tile[dk0 + 3][df] << 48);
    *(u64*)(out + (size_t)(j0 + df) * 2048 + k0 + dk0) = w;
  }
}

// ===================== V transpose: C1 V-section -> VT[bh][d(128)][s(2048)] =====================
__global__ __launch_bounds__(256) void vtrans(const u16* __restrict__ C1, u16* __restrict__ VT) {
  __shared__ u16 tile[64][72];
  int t = threadIdx.x;
  int s0 = blockIdx.x * 64;
  int bh = blockIdx.y >> 1;
  int d0 = (blockIdx.y & 1) * 64;
  int b = bh >> 4, h = bh & 15;
  const u16* src = C1 + (size_t)(b * 2048 + s0) * 6144 + 4096 + h * 128 + d0;
#pragma unroll
  for (int it = 0; it < 2; ++it) {
    int ss = it * 32 + (t >> 3);
    int dd = (t & 7) * 8;
    uint4 v = *(const uint4*)(src + (size_t)ss * 6144 + dd);
    *(uint4*)&tile[ss][dd] = v;
  }
  __syncthreads();
#pragma unroll
  for (int it = 0; it < 2; ++it) {
    int dd = it * 32 + (t >> 3);
    int ss0 = (t & 7) * 8;
    union { u16 q[8]; uint4 v; } u;
#pragma unroll
    for (int i = 0; i < 8; ++i) u.q[i] = tile[ss0 + i][dd];
    *(uint4*)(VT + (size_t)(bh * 128 + d0 + dd) * 2048 + s0 + ss0) = u.v;
  }
}

// ===================== GEMM: C[M][N] = A[M][2048] @ Bt[N][2048]^T =====================
template <int MODE>
__global__ __launch_bounds__(256, 2) void gemm_bt(const u16* __restrict__ A,
                                                  const u16* __restrict__ Bt,
                                                  void* __restrict__ Cout) {
  const int K = 2048;
  __shared__ u16 lds[2][2][8192];  // [dbuf][A,B][128*64]
  int tid = threadIdx.x;
  int lane = tid & 63;
  int c = lane & 15, g = lane >> 4;
  int wid = tid >> 6;
  int wr = wid >> 1, wc = wid & 1;
  size_t m0 = (size_t)blockIdx.y * 128;
  size_t n0 = (size_t)blockIdx.x * 128;
  const u16* Asrc = A + m0 * K;
  const u16* Bsrc = Bt + n0 * K;

  f32x4 acc[4][4];
#pragma unroll
  for (int i = 0; i < 4; ++i)
#pragma unroll
    for (int j = 0; j < 4; ++j) acc[i][j] = f32x4{0.f, 0.f, 0.f, 0.f};

  auto stage = [&](int buf, int kt) {
#pragma unroll
    for (int i = 0; i < 4; ++i) {
      int p = i * 4096 + tid * 16;
      int row = p >> 7;
      int inner = (p & 127) ^ ((row & 7) << 4);
      int col = (kt * 128 + inner) >> 1;
      __builtin_amdgcn_global_load_lds((glb32_t*)(Asrc + (size_t)row * K + col),
                                       (lds32_t*)(&lds[buf][0][p >> 1]), 16, 0, 0);
      __builtin_amdgcn_global_load_lds((glb32_t*)(Bsrc + (size_t)row * K + col),
                                       (lds32_t*)(&lds[buf][1][p >> 1]), 16, 0, 0);
    }
  };

  stage(0, 0);
  asm volatile("s_waitcnt vmcnt(0)" ::: "memory");
  __syncthreads();
  int cur = 0;
  for (int kt = 0; kt < 32; ++kt) {
    if (kt + 1 < 32) stage(cur ^ 1, kt + 1);
    const u16* Ab = &lds[cur][0][0];
    const u16* Bb = &lds[cur][1][0];
#pragma unroll
    for (int kk = 0; kk < 2; ++kk) {
      bf16x8 af[4], bfr[4];
#pragma unroll
      for (int i = 0; i < 4; ++i) {
        int rowA = wr * 64 + i * 16 + c;
        int offA = rowA * 128 + ((kk * 64 + g * 16) ^ ((rowA & 7) << 4));
        af[i] = *(const bf16x8*)(Ab + (offA >> 1));
        int rowB = wc * 64 + i * 16 + c;
        int offB = rowB * 128 + ((kk * 64 + g * 16) ^ ((rowB & 7) << 4));
        bfr[i] = *(const bf16x8*)(Bb + (offB >> 1));
      }
#pragma unroll
      for (int i = 0; i < 4; ++i)
#pragma unroll
        for (int j = 0; j < 4; ++j) acc[i][j] = mfma16(af[i], bfr[j], acc[i][j]);
    }
    __syncthreads();
    cur ^= 1;
  }

  if (MODE == 0) {
    u16* C = (u16*)Cout;
#pragma unroll
    for (int i = 0; i < 4; ++i)
#pragma unroll
      for (int j = 0; j < 4; ++j) {
        size_t row = m0 + wr * 64 + i * 16 + g * 4;
        size_t col = n0 + wc * 64 + j * 16 + c;
#pragma unroll
        for (int r = 0; r < 4; ++r) C[(row + r) * 6144 + col] = f2bf(acc[i][j][r]);
      }
  } else {
    float* Y = (float*)Cout;
#pragma unroll
    for (int i = 0; i < 4; ++i)
#pragma unroll
      for (int j = 0; j < 4; ++j) {
        size_t row = m0 + wr * 64 + i * 16 + g * 4;
        int col = (int)(n0 + wc * 64 + j * 16 + c);
        float* base = (col < 1024) ? (Y + col) : (Y + 4194304 + (col - 1024));
#pragma unroll
        for (int r = 0; r < 4; ++r) base[(row + r) * 1024] = acc[i][j][r];
      }
  }
}

// ===================== Flash attention v2 =====================
// 4 waves/block (64 q-rows), KVBLK=32, K+V double-buffered in LDS.
// Swapped QK^T (mfma(K,Q)) -> per-lane softmax over 8 kv values, 8 shfl/tile.
// K staged via global_load_lds w16 with XOR swizzle (slot ^ row&15);
// V reg-staged (issue-early/write-late) into padded [128][40] layout.
__global__ __launch_bounds__(256) void attn_fwd(const u16* __restrict__ C1,
                                                const u16* __restrict__ VT,
                                                u16* __restrict__ O) {
  __shared__ u16 Kl[2][4096];   // [32 kv][128 d], 256B rows, XOR-swizzled 16B slots
  __shared__ u16 Vl[2][5120];   // [128 d][40], kv in slots 0..31, pad 8
  __shared__ u16 Pl[4][640];    // per-wave P[q=16][40], kv in 0..31

  int tid = threadIdx.x;
  int lane = tid & 63;
  int w = tid >> 6;
  int c = lane & 15, g = lane >> 4;
  int qt = blockIdx.x;
  int bh = blockIdx.y;
  int b = bh >> 4, h = bh & 15;
  const size_t LDC = 6144;
  const u16* Qb = C1 + (size_t)(b * 2048 + qt * 64 + w * 16) * LDC + h * 128;
  const u16* Ks = C1 + (size_t)(b * 2048) * LDC + 2048 + h * 128;
  const u16* Vs = VT + (size_t)bh * 128 * 2048;
  u16* Pw = Pl[w];

  bf16x8 qf[4];
#pragma unroll
  for (int kk = 0; kk < 4; ++kk)
    qf[kk] = *(const bf16x8*)(Qb + (size_t)c * LDC + kk * 32 + g * 8);

  float mrun = -1e30f, lrun = 0.f;
  f32x4 o[8];
#pragma unroll
  for (int nt = 0; nt < 8; ++nt) o[nt] = f32x4{0.f, 0.f, 0.f, 0.f};

  const float SC = 0.125f * 1.44269504f;  // SCALE * log2(e)
  const int vd = tid >> 2, vs = tid & 3;  // V staging indices
  const int kr = tid >> 4, ksl = tid & 15;  // K staging indices

  // prologue: stage tile 0
  {
    uint4 vr0 = *(const uint4*)(Vs + (size_t)vd * 2048 + vs * 8);
    uint4 vr1 = *(const uint4*)(Vs + (size_t)(64 + vd) * 2048 + vs * 8);
#pragma unroll
    for (int i = 0; i < 2; ++i) {
      int row = i * 16 + kr;
      __builtin_amdgcn_global_load_lds(
          (glb32_t*)(Ks + (size_t)row * LDC + ((ksl ^ (row & 15)) << 3)),
          (lds32_t*)&Kl[0][(i * 256 + tid) * 8], 16, 0, 0);
    }
    *(uint4*)&Vl[0][vd * 40 + vs * 8] = vr0;
    *(uint4*)&Vl[0][(64 + vd) * 40 + vs * 8] = vr1;
  }
  __syncthreads();

  int cur = 0;
  uint4 vreg[2];
  for (int t = 0; t < 64; ++t) {
    if (t < 63) {
      int kvn = (t + 1) * 32;
      vreg[0] = *(const uint4*)(Vs + (size_t)vd * 2048 + kvn + vs * 8);
      vreg[1] = *(const uint4*)(Vs + (size_t)(64 + vd) * 2048 + kvn + vs * 8);
#pragma unroll
      for (int i = 0; i < 2; ++i) {
        int row = i * 16 + kr;
        __builtin_amdgcn_global_load_lds(
            (glb32_t*)(Ks + (size_t)(kvn + row) * LDC + ((ksl ^ (row & 15)) << 3)),
            (lds32_t*)&Kl[cur ^ 1][(i * 256 + tid) * 8], 16, 0, 0);
      }
    }

    // ---- QK^T (swapped: S^T[kv][q]) ----
    f32x4 s0 = f32x4{0.f, 0.f, 0.f, 0.f};
    f32x4 s1 = f32x4{0.f, 0.f, 0.f, 0.f};
#pragma unroll
    for (int kk = 0; kk < 4; ++kk) {
      int sl = ((4 * kk + g) ^ c) << 3;
      bf16x8 kf0 = *(const bf16x8*)&Kl[cur][c * 128 + sl];
      bf16x8 kf1 = *(const bf16x8*)&Kl[cur][(c + 16) * 128 + sl];
      s0 = mfma16(kf0, qf[kk], s0);
      s1 = mfma16(kf1, qf[kk], s1);
    }

    // ---- per-lane softmax (q = c, 8 kv values) ----
    float sv[8];
#pragma unroll
    for (int r = 0; r < 4; ++r) { sv[r] = s0[r] * SC; sv[4 + r] = s1[r] * SC; }
    float mx = sv[0];
#pragma unroll
    for (int j = 1; j < 8; ++j) mx = fmaxf(mx, sv[j]);
    mx = fmaxf(mx, __shfl_xor(mx, 16));
    mx = fmaxf(mx, __shfl_xor(mx, 32));
    float mn = fmaxf(mrun, mx);
    float al = exp2f(mrun - mn);
    mrun = mn;
    float p[8], sm = 0.f;
#pragma unroll
    for (int j = 0; j < 8; ++j) { p[j] = exp2f(sv[j] - mn); sm += p[j]; }
    sm += __shfl_xor(sm, 16);
    sm += __shfl_xor(sm, 32);
    lrun = lrun * al + sm;

    // rescale O (redistribute al from q=c orientation to q=4g+r orientation)
    float alr[4];
#pragma unroll
    for (int r = 0; r < 4; ++r) alr[r] = __shfl(al, 4 * g + r);
#pragma unroll
    for (int nt = 0; nt < 8; ++nt)
#pragma unroll
      for (int r = 0; r < 4; ++r) o[nt][r] *= alr[r];

    // ---- P exchange through wave-private LDS ----
    asm volatile("" ::: "memory");
    *(u32*)&Pw[c * 40 + 4 * g] = pk2(p[0], p[1]);
    *(u32*)&Pw[c * 40 + 4 * g + 2] = pk2(p[2], p[3]);
    *(u32*)&Pw[c * 40 + 16 + 4 * g] = pk2(p[4], p[5]);
    *(u32*)&Pw[c * 40 + 18 + 4 * g] = pk2(p[6], p[7]);
    asm volatile("" ::: "memory");
    bf16x8 pa = *(const bf16x8*)&Pw[c * 40 + g * 8];

    // ---- PV ----
#pragma unroll
    for (int nt = 0; nt < 8; ++nt) {
      bf16x8 vf = *(const bf16x8*)&Vl[cur][(nt * 16 + c) * 40 + g * 8];
      o[nt] = mfma16(pa, vf, o[nt]);
    }

    if (t < 63) {
      *(uint4*)&Vl[cur ^ 1][vd * 40 + vs * 8] = vreg[0];
      *(uint4*)&Vl[cur ^ 1][(64 + vd) * 40 + vs * 8] = vreg[1];
    }
    __syncthreads();
    cur ^= 1;
  }

  float inv = 1.0f / lrun;
  float invr[4];
#pragma unroll
  for (int r = 0; r < 4; ++r) invr[r] = __shfl(inv, 4 * g + r);
#pragma unroll
  for (int nt = 0; nt < 8; ++nt)
#pragma unroll
    for (int r = 0; r < 4; ++r) {
      size_t row = (size_t)(b * 2048 + qt * 64 + w * 16 + 4 * g + r);
      O[row * 2048 + h * 128 + nt * 16 + c] = f2bf(o[nt][r] * invr[r]);
    }
}

// ===================== launch =====================
extern "C" void kernel_launch(void* const* d_in, const int* in_sizes, int n_in,
                              void* d_out, int out_size, void* d_ws, size_t ws_size,
                              hipStream_t stream) {
  const float* zr   = (const float*)d_in[0];
  const float* zi   = (const float*)d_in[1];
  const float* wq_r = (const float*)d_in[2];
  const float* wq_i = (const float*)d_in[3];
  const float* wk_r = (const float*)d_in[4];
  const float* wk_i = (const float*)d_in[5];
  const float* wv_r = (const float*)d_in[6];
  const float* wv_i = (const float*)d_in[7];
  const float* wo_r = (const float*)d_in[8];
  const float* wo_i = (const float*)d_in[9];

  if (ws_size < (size_t)134217728) return;  // need 128 MiB scratch

  char* ws = (char*)d_ws;
  u16* X    = (u16*)(ws + 0);          //  16 MiB: [4096][2048]
  u16* Wqkv = (u16*)(ws + 16777216);   //  24 MiB: [6144][2048]
  u16* C1   = (u16*)(ws + 41943040);   //  48 MiB: [4096][6144] = [Q|K|V] head-interleaved
  u16* VT   = (u16*)(ws + 92274688);   //  16 MiB: [32][128][2048]
  u16* O    = (u16*)(ws + 109051904);  //  16 MiB: [4096][2048]
  u16* Wo   = (u16*)(ws + 125829120);  //   8 MiB: [2048][2048]

  pack_x<<<8192, 256, 0, stream>>>(zr, zi, X);
  pack_w<0><<<dim3(96, 32), 256, 0, stream>>>(wq_r, wq_i, wk_r, wk_i, wv_r, wv_i, Wqkv);
  pack_w<1><<<dim3(32, 32), 256, 0, stream>>>(wo_r, wo_i, wo_r, wo_i, wo_r, wo_i, Wo);
  gemm_bt<0><<<dim3(48, 32), 256, 0, stream>>>(X, Wqkv, C1);
  vtrans<<<dim3(32, 64), 256, 0, stream>>>(C1, VT);
  attn_fwd<<<dim3(32, 32), 256, 0, stream>>>(C1, VT, O);
  gemm_bt<1><<<dim3(16, 32), 256, 0, stream>>>(O, Wo, (float*)d_out);
}

// Round 3
// 387.237 us; speedup vs baseline: 2.1080x; 1.1377x over previous
//
#include <hip/hip_runtime.h>

typedef unsigned short u16;
typedef unsigned int u32;
typedef unsigned long long u64;
typedef __bf16 bf16_t;
typedef bf16_t bf16x8 __attribute__((ext_vector_type(8)));
typedef float f32x4 __attribute__((ext_vector_type(4)));

typedef __attribute__((address_space(3))) u32 lds32_t;
typedef __attribute__((address_space(1))) u32 glb32_t;

#define DEV static __device__ __forceinline__

DEV f32x4 mfma16(bf16x8 a, bf16x8 b, f32x4 c) {
  return __builtin_amdgcn_mfma_f32_16x16x32_bf16(a, b, c, 0, 0, 0);
}

DEV u16 f2bf(float f) { return __builtin_bit_cast(u16, (bf16_t)f); }

// ===================== pack X: [4096][2048] bf16 = [zr | zi] =====================
__global__ __launch_bounds__(256) void pack_x(const float* __restrict__ zr,
                                              const float* __restrict__ zi,
                                              u16* __restrict__ X) {
  int idx = (blockIdx.x * 256 + threadIdx.x) * 4;
  int m = idx >> 11;
  int k = idx & 2047;
  const float* s = (k < 1024) ? (zr + m * 1024 + k) : (zi + m * 1024 + (k - 1024));
  f32x4 v = *(const f32x4*)s;
  u16* o = X + idx;
  o[0] = f2bf(v[0]); o[1] = f2bf(v[1]); o[2] = f2bf(v[2]); o[3] = f2bf(v[3]);
}

// ===================== pack weights into B^T layout [J][2048] bf16 =====================
template <int MODE>
__global__ __launch_bounds__(256) void pack_w(const float* __restrict__ w0r, const float* __restrict__ w0i,
                                              const float* __restrict__ w1r, const float* __restrict__ w1i,
                                              const float* __restrict__ w2r, const float* __restrict__ w2i,
                                              u16* __restrict__ out) {
  __shared__ u16 tile[64][68];
  int t = threadIdx.x;
  int j0 = blockIdx.x * 64;
  int k0 = blockIdx.y * 64;
  const float* src;
  float sign = 1.0f;
  int f0, r0;
  if (MODE == 0) {
    int section = j0 >> 11;
    int jj = j0 & 2047;
    int h = jj >> 7;
    bool real = ((jj & 127) < 64);
    f0 = h * 64;
    const float* wr = (section == 0) ? w0r : ((section == 1) ? w1r : w2r);
    const float* wi = (section == 0) ? w0i : ((section == 1) ? w1i : w2i);
    bool lowk = (k0 < 1024);
    r0 = lowk ? k0 : (k0 - 1024);
    if (real) { src = lowk ? wr : wi; sign = lowk ? 1.0f : -1.0f; }
    else      { src = lowk ? wi : wr; sign = 1.0f; }
  } else {
    int h = k0 >> 7;
    bool treal = ((k0 & 127) < 64);
    r0 = h * 64;
    bool lowj = (j0 < 1024);
    f0 = lowj ? j0 : (j0 - 1024);
    if (treal) { src = lowj ? w0r : w0i; sign = 1.0f; }
    else       { src = lowj ? w0i : w0r; sign = lowj ? -1.0f : 1.0f; }
  }
#pragma unroll
  for (int it = 0; it < 4; ++it) {
    int dk = it * 16 + (t >> 4);
    int df = (t & 15) * 4;
    f32x4 v = *(const f32x4*)(src + (size_t)(r0 + dk) * 1024 + f0 + df);
    u64 w = (u64)f2bf(sign * v[0]) | ((u64)f2bf(sign * v[1]) << 16) |
            ((u64)f2bf(sign * v[2]) << 32) | ((u64)f2bf(sign * v[3]) << 48);
    *(u64*)&tile[dk][df] = w;
  }
  __syncthreads();
#pragma unroll
  for (int it = 0; it < 4; ++it) {
    int df = it * 16 + (t >> 4);
    int dk0 = (t & 15) * 4;
    u64 w = (u64)tile[dk0][df] | ((u64)tile[dk0 + 1][df] << 16) |
            ((u64)tile[dk0 + 2][df] << 32) | ((u64)tile[dk0 + 3][df] << 48);
    *(u64*)(out + (size_t)(j0 + df) * 2048 + k0 + dk0) = w;
  }
}

// ===================== V transpose: C1 V-section -> VT[bh][d(128)][s(2048)] =====================
__global__ __launch_bounds__(256) void vtrans(const u16* __restrict__ C1, u16* __restrict__ VT) {
  __shared__ u16 tile[64][72];
  int t = threadIdx.x;
  int s0 = blockIdx.x * 64;
  int bh = blockIdx.y >> 1;
  int d0 = (blockIdx.y & 1) * 64;
  int b = bh >> 4, h = bh & 15;
  const u16* src = C1 + (size_t)(b * 2048 + s0) * 6144 + 4096 + h * 128 + d0;
#pragma unroll
  for (int it = 0; it < 2; ++it) {
    int ss = it * 32 + (t >> 3);
    int dd = (t & 7) * 8;
    uint4 v = *(const uint4*)(src + (size_t)ss * 6144 + dd);
    *(uint4*)&tile[ss][dd] = v;
  }
  __syncthreads();
#pragma unroll
  for (int it = 0; it < 2; ++it) {
    int dd = it * 32 + (t >> 3);
    int ss0 = (t & 7) * 8;
    union { u16 q[8]; uint4 v; } u;
#pragma unroll
    for (int i = 0; i < 8; ++i) u.q[i] = tile[ss0 + i][dd];
    *(uint4*)(VT + (size_t)(bh * 128 + d0 + dd) * 2048 + s0 + ss0) = u.v;
  }
}

// ===================== GEMM: C[M][N] = A[M][2048] @ Bt[N][2048]^T =====================
template <int MODE>
__global__ __launch_bounds__(256, 2) void gemm_bt(const u16* __restrict__ A,
                                                  const u16* __restrict__ Bt,
                                                  void* __restrict__ Cout) {
  const int K = 2048;
  __shared__ u16 lds[2][2][8192];  // [dbuf][A,B][128*64]
  int tid = threadIdx.x;
  int lane = tid & 63;
  int c = lane & 15, g = lane >> 4;
  int wid = tid >> 6;
  int wr = wid >> 1, wc = wid & 1;
  size_t m0 = (size_t)blockIdx.y * 128;
  size_t n0 = (size_t)blockIdx.x * 128;
  const u16* Asrc = A + m0 * K;
  const u16* Bsrc = Bt + n0 * K;

  f32x4 acc[4][4];
#pragma unroll
  for (int i = 0; i < 4; ++i)
#pragma unroll
    for (int j = 0; j < 4; ++j) acc[i][j] = f32x4{0.f, 0.f, 0.f, 0.f};

  auto stage = [&](int buf, int kt) {
#pragma unroll
    for (int i = 0; i < 4; ++i) {
      int p = i * 4096 + tid * 16;
      int row = p >> 7;
      int inner = (p & 127) ^ ((row & 7) << 4);
      int col = (kt * 128 + inner) >> 1;
      __builtin_amdgcn_global_load_lds((glb32_t*)(Asrc + (size_t)row * K + col),
                                       (lds32_t*)(&lds[buf][0][p >> 1]), 16, 0, 0);
      __builtin_amdgcn_global_load_lds((glb32_t*)(Bsrc + (size_t)row * K + col),
                                       (lds32_t*)(&lds[buf][1][p >> 1]), 16, 0, 0);
    }
  };

  stage(0, 0);
  asm volatile("s_waitcnt vmcnt(0)" ::: "memory");
  __syncthreads();
  int cur = 0;
  for (int kt = 0; kt < 32; ++kt) {
    if (kt + 1 < 32) stage(cur ^ 1, kt + 1);
    const u16* Ab = &lds[cur][0][0];
    const u16* Bb = &lds[cur][1][0];
#pragma unroll
    for (int kk = 0; kk < 2; ++kk) {
      bf16x8 af[4], bfr[4];
#pragma unroll
      for (int i = 0; i < 4; ++i) {
        int rowA = wr * 64 + i * 16 + c;
        int offA = rowA * 128 + ((kk * 64 + g * 16) ^ ((rowA & 7) << 4));
        af[i] = *(const bf16x8*)(Ab + (offA >> 1));
        int rowB = wc * 64 + i * 16 + c;
        int offB = rowB * 128 + ((kk * 64 + g * 16) ^ ((rowB & 7) << 4));
        bfr[i] = *(const bf16x8*)(Bb + (offB >> 1));
      }
#pragma unroll
      for (int i = 0; i < 4; ++i)
#pragma unroll
        for (int j = 0; j < 4; ++j) acc[i][j] = mfma16(af[i], bfr[j], acc[i][j]);
    }
    __syncthreads();
    cur ^= 1;
  }

  if (MODE == 0) {
    u16* C = (u16*)Cout;
#pragma unroll
    for (int i = 0; i < 4; ++i)
#pragma unroll
      for (int j = 0; j < 4; ++j) {
        size_t row = m0 + wr * 64 + i * 16 + g * 4;
        size_t col = n0 + wc * 64 + j * 16 + c;
#pragma unroll
        for (int r = 0; r < 4; ++r) C[(row + r) * 6144 + col] = f2bf(acc[i][j][r]);
      }
  } else {
    float* Y = (float*)Cout;
#pragma unroll
    for (int i = 0; i < 4; ++i)
#pragma unroll
      for (int j = 0; j < 4; ++j) {
        size_t row = m0 + wr * 64 + i * 16 + g * 4;
        int col = (int)(n0 + wc * 64 + j * 16 + c);
        float* base = (col < 1024) ? (Y + col) : (Y + 4194304 + (col - 1024));
#pragma unroll
        for (int r = 0; r < 4; ++r) base[(row + r) * 1024] = acc[i][j][r];
      }
  }
}

// ===================== Flash attention v3 =====================
// 8 waves/block (128 q-rows), KVBLK=32, K+V double-buffered in LDS shared by all waves.
// Swapped QK^T -> per-lane softmax; defer-max (T13, THR=8 log2); native bf16 cvt;
// exp via fmaf-folded scale. K via global_load_lds w16 + XOR swizzle; V reg-staged (T14).
__global__ __launch_bounds__(512) void attn_fwd(const u16* __restrict__ C1,
                                                const u16* __restrict__ VT,
                                                u16* __restrict__ O) {
  __shared__ u16 Kl[2][4096];   // [32 kv][128 d], XOR-swizzled 16B slots
  __shared__ u16 Vl[2][5120];   // [128 d][40], kv in slots 0..31, pad 8
  __shared__ u16 Pl[8][640];    // per-wave P[q=16][40]

  int tid = threadIdx.x;
  int lane = tid & 63;
  int w = tid >> 6;
  int c = lane & 15, g = lane >> 4;
  int qt = blockIdx.x;
  int bh = blockIdx.y;
  int b = bh >> 4, h = bh & 15;
  const size_t LDC = 6144;
  const u16* Qb = C1 + (size_t)(b * 2048 + qt * 128 + w * 16) * LDC + h * 128;
  const u16* Ks = C1 + (size_t)(b * 2048) * LDC + 2048 + h * 128;
  const u16* Vs = VT + (size_t)bh * 128 * 2048;
  u16* Pw = Pl[w];

  bf16x8 qf[4];
#pragma unroll
  for (int kk = 0; kk < 4; ++kk)
    qf[kk] = *(const bf16x8*)(Qb + (size_t)c * LDC + kk * 32 + g * 8);

  float mrunS = -3e38f, lrun = 0.f;
  f32x4 o[8];
#pragma unroll
  for (int nt = 0; nt < 8; ++nt) o[nt] = f32x4{0.f, 0.f, 0.f, 0.f};

  const float SC = 0.125f * 1.44269504f;  // SCALE * log2(e)
  const int kr = tid >> 4, ksl = tid & 15;  // K staging: 32 rows x 16 slots
  const int vd = tid >> 2, vs = tid & 3;    // V staging: 128 rows x 4 slots

  // prologue: stage tile 0 (1 gload_lds + 1 uint4 per thread)
  {
    uint4 vr = *(const uint4*)(Vs + (size_t)vd * 2048 + vs * 8);
    __builtin_amdgcn_global_load_lds(
        (glb32_t*)(Ks + (size_t)kr * LDC + ((ksl ^ (kr & 15)) << 3)),
        (lds32_t*)&Kl[0][tid * 8], 16, 0, 0);
    *(uint4*)&Vl[0][vd * 40 + vs * 8] = vr;
  }
  __syncthreads();

  int cur = 0;
  uint4 vreg;
  for (int t = 0; t < 64; ++t) {
    if (t < 63) {
      int kvn = (t + 1) * 32;
      vreg = *(const uint4*)(Vs + (size_t)vd * 2048 + kvn + vs * 8);
      __builtin_amdgcn_global_load_lds(
          (glb32_t*)(Ks + (size_t)(kvn + kr) * LDC + ((ksl ^ (kr & 15)) << 3)),
          (lds32_t*)&Kl[cur ^ 1][tid * 8], 16, 0, 0);
    }

    // ---- QK^T (swapped: S^T[kv][q]) ----
    f32x4 s0 = f32x4{0.f, 0.f, 0.f, 0.f};
    f32x4 s1 = f32x4{0.f, 0.f, 0.f, 0.f};
#pragma unroll
    for (int kk = 0; kk < 4; ++kk) {
      int sl = ((4 * kk + g) ^ c) << 3;
      bf16x8 kf0 = *(const bf16x8*)&Kl[cur][c * 128 + sl];
      bf16x8 kf1 = *(const bf16x8*)&Kl[cur][(c + 16) * 128 + sl];
      s0 = mfma16(kf0, qf[kk], s0);
      s1 = mfma16(kf1, qf[kk], s1);
    }

    // ---- per-lane softmax (q = c, 8 kv values), defer-max ----
    float sv[8];
#pragma unroll
    for (int r = 0; r < 4; ++r) { sv[r] = s0[r]; sv[4 + r] = s1[r]; }
    float mx = fmaxf(fmaxf(fmaxf(sv[0], sv[1]), fmaxf(sv[2], sv[3])),
                     fmaxf(fmaxf(sv[4], sv[5]), fmaxf(sv[6], sv[7])));
    mx = fmaxf(mx, __shfl_xor(mx, 16));
    mx = fmaxf(mx, __shfl_xor(mx, 32));
    float mxs = mx * SC;
    if (!__all(mxs <= mrunS + 8.0f)) {   // rare rescale (wave-uniform branch)
      float mn = fmaxf(mrunS, mxs);
      float al = exp2f(mrunS - mn);
      mrunS = mn;
      float alr[4];
#pragma unroll
      for (int r = 0; r < 4; ++r) alr[r] = __shfl(al, 4 * g + r);
#pragma unroll
      for (int nt = 0; nt < 8; ++nt)
#pragma unroll
        for (int r = 0; r < 4; ++r) o[nt][r] *= alr[r];
      lrun *= al;
    }
    float p[8], sm = 0.f;
#pragma unroll
    for (int j = 0; j < 8; ++j) { p[j] = exp2f(fmaf(sv[j], SC, -mrunS)); sm += p[j]; }
    sm += __shfl_xor(sm, 16);
    sm += __shfl_xor(sm, 32);
    lrun += sm;

    // ---- P exchange through wave-private LDS (bf16 via native cvt_pk) ----
    union { bf16_t q[8]; u32 d[4]; } pu;
#pragma unroll
    for (int j = 0; j < 8; ++j) pu.q[j] = (bf16_t)p[j];
    asm volatile("" ::: "memory");
    *(u32*)&Pw[c * 40 + 4 * g] = pu.d[0];
    *(u32*)&Pw[c * 40 + 4 * g + 2] = pu.d[1];
    *(u32*)&Pw[c * 40 + 16 + 4 * g] = pu.d[2];
    *(u32*)&Pw[c * 40 + 18 + 4 * g] = pu.d[3];
    asm volatile("" ::: "memory");
    bf16x8 pa = *(const bf16x8*)&Pw[c * 40 + g * 8];

    // ---- PV ----
#pragma unroll
    for (int nt = 0; nt < 8; ++nt) {
      bf16x8 vf = *(const bf16x8*)&Vl[cur][(nt * 16 + c) * 40 + g * 8];
      o[nt] = mfma16(pa, vf, o[nt]);
    }

    if (t < 63) *(uint4*)&Vl[cur ^ 1][vd * 40 + vs * 8] = vreg;
    __syncthreads();
    cur ^= 1;
  }

  float inv = 1.0f / lrun;
  float invr[4];
#pragma unroll
  for (int r = 0; r < 4; ++r) invr[r] = __shfl(inv, 4 * g + r);
#pragma unroll
  for (int nt = 0; nt < 8; ++nt)
#pragma unroll
    for (int r = 0; r < 4; ++r) {
      size_t row = (size_t)(b * 2048 + qt * 128 + w * 16 + 4 * g + r);
      O[row * 2048 + h * 128 + nt * 16 + c] = f2bf(o[nt][r] * invr[r]);
    }
}

// ===================== launch =====================
extern "C" void kernel_launch(void* const* d_in, const int* in_sizes, int n_in,
                              void* d_out, int out_size, void* d_ws, size_t ws_size,
                              hipStream_t stream) {
  const float* zr   = (const float*)d_in[0];
  const float* zi   = (const float*)d_in[1];
  const float* wq_r = (const float*)d_in[2];
  const float* wq_i = (const float*)d_in[3];
  const float* wk_r = (const float*)d_in[4];
  const float* wk_i = (const float*)d_in[5];
  const float* wv_r = (const float*)d_in[6];
  const float* wv_i = (const float*)d_in[7];
  const float* wo_r = (const float*)d_in[8];
  const float* wo_i = (const float*)d_in[9];

  if (ws_size < (size_t)134217728) return;  // need 128 MiB scratch

  char* ws = (char*)d_ws;
  u16* X    = (u16*)(ws + 0);          //  16 MiB: [4096][2048]
  u16* Wqkv = (u16*)(ws + 16777216);   //  24 MiB: [6144][2048]
  u16* C1   = (u16*)(ws + 41943040);   //  48 MiB: [4096][6144] = [Q|K|V] head-interleaved
  u16* VT   = (u16*)(ws + 92274688);   //  16 MiB: [32][128][2048]
  u16* O    = (u16*)(ws + 109051904);  //  16 MiB: [4096][2048]
  u16* Wo   = (u16*)(ws + 125829120);  //   8 MiB: [2048][2048]

  pack_x<<<8192, 256, 0, stream>>>(zr, zi, X);
  pack_w<0><<<dim3(96, 32), 256, 0, stream>>>(wq_r, wq_i, wk_r, wk_i, wv_r, wv_i, Wqkv);
  pack_w<1><<<dim3(32, 32), 256, 0, stream>>>(wo_r, wo_i, wo_r, wo_i, wo_r, wo_i, Wo);
  gemm_bt<0><<<dim3(48, 32), 256, 0, stream>>>(X, Wqkv, C1);
  vtrans<<<dim3(32, 64), 256, 0, stream>>>(C1, VT);
  attn_fwd<<<dim3(16, 32), 512, 0, stream>>>(C1, VT, O);
  gemm_bt<1><<<dim3(16, 32), 256, 0, stream>>>(O, Wo, (float*)d_out);
}

// Round 5
// 375.990 us; speedup vs baseline: 2.1710x; 1.0299x over previous
//
#include <hip/hip_runtime.h>

typedef unsigned short u16;
typedef unsigned int u32;
typedef unsigned long long u64;
typedef __bf16 bf16_t;
typedef bf16_t bf16x8 __attribute__((ext_vector_type(8)));
typedef float f32x4 __attribute__((ext_vector_type(4)));

typedef __attribute__((address_space(3))) u32 lds32_t;
typedef __attribute__((address_space(1))) u32 glb32_t;

#define DEV static __device__ __forceinline__

DEV f32x4 mfma16(bf16x8 a, bf16x8 b, f32x4 c) {
  return __builtin_amdgcn_mfma_f32_16x16x32_bf16(a, b, c, 0, 0, 0);
}

DEV u16 f2bf(float f) { return __builtin_bit_cast(u16, (bf16_t)f); }
DEV u32 pk2(float a, float b) {
  return (u32)__builtin_bit_cast(u16, (bf16_t)a) |
         ((u32)__builtin_bit_cast(u16, (bf16_t)b) << 16);
}

// ===================== pack X: [4096][2048] bf16 = [zr | zi] =====================
__global__ __launch_bounds__(256) void pack_x(const float* __restrict__ zr,
                                              const float* __restrict__ zi,
                                              u16* __restrict__ X) {
  int idx = (blockIdx.x * 256 + threadIdx.x) * 4;
  int m = idx >> 11;
  int k = idx & 2047;
  const float* s = (k < 1024) ? (zr + m * 1024 + k) : (zi + m * 1024 + (k - 1024));
  f32x4 v = *(const f32x4*)s;
  u16* o = X + idx;
  o[0] = f2bf(v[0]); o[1] = f2bf(v[1]); o[2] = f2bf(v[2]); o[3] = f2bf(v[3]);
}

// ===================== pack weights into B^T layout [J][2048] bf16 =====================
template <int MODE>
__global__ __launch_bounds__(256) void pack_w(const float* __restrict__ w0r, const float* __restrict__ w0i,
                                              const float* __restrict__ w1r, const float* __restrict__ w1i,
                                              const float* __restrict__ w2r, const float* __restrict__ w2i,
                                              u16* __restrict__ out) {
  __shared__ u16 tile[64][68];
  int t = threadIdx.x;
  int j0 = blockIdx.x * 64;
  int k0 = blockIdx.y * 64;
  const float* src;
  float sign = 1.0f;
  int f0, r0;
  if (MODE == 0) {
    int section = j0 >> 11;
    int jj = j0 & 2047;
    int h = jj >> 7;
    bool real = ((jj & 127) < 64);
    f0 = h * 64;
    const float* wr = (section == 0) ? w0r : ((section == 1) ? w1r : w2r);
    const float* wi = (section == 0) ? w0i : ((section == 1) ? w1i : w2i);
    bool lowk = (k0 < 1024);
    r0 = lowk ? k0 : (k0 - 1024);
    if (real) { src = lowk ? wr : wi; sign = lowk ? 1.0f : -1.0f; }
    else      { src = lowk ? wi : wr; sign = 1.0f; }
  } else {
    int h = k0 >> 7;
    bool treal = ((k0 & 127) < 64);
    r0 = h * 64;
    bool lowj = (j0 < 1024);
    f0 = lowj ? j0 : (j0 - 1024);
    if (treal) { src = lowj ? w0r : w0i; sign = 1.0f; }
    else       { src = lowj ? w0i : w0r; sign = lowj ? -1.0f : 1.0f; }
  }
#pragma unroll
  for (int it = 0; it < 4; ++it) {
    int dk = it * 16 + (t >> 4);
    int df = (t & 15) * 4;
    f32x4 v = *(const f32x4*)(src + (size_t)(r0 + dk) * 1024 + f0 + df);
    u64 w = (u64)f2bf(sign * v[0]) | ((u64)f2bf(sign * v[1]) << 16) |
            ((u64)f2bf(sign * v[2]) << 32) | ((u64)f2bf(sign * v[3]) << 48);
    *(u64*)&tile[dk][df] = w;
  }
  __syncthreads();
#pragma unroll
  for (int it = 0; it < 4; ++it) {
    int df = it * 16 + (t >> 4);
    int dk0 = (t & 15) * 4;
    u64 w = (u64)tile[dk0][df] | ((u64)tile[dk0 + 1][df] << 16) |
            ((u64)tile[dk0 + 2][df] << 32) | ((u64)tile[dk0 + 3][df] << 48);
    *(u64*)(out + (size_t)(j0 + df) * 2048 + k0 + dk0) = w;
  }
}

// ===================== V transpose: C1 V-section -> VT[bh][d(128)][s(2048)] =====================
__global__ __launch_bounds__(256) void vtrans(const u16* __restrict__ C1, u16* __restrict__ VT) {
  __shared__ u16 tile[64][72];
  int t = threadIdx.x;
  int s0 = blockIdx.x * 64;
  int bh = blockIdx.y >> 1;
  int d0 = (blockIdx.y & 1) * 64;
  int b = bh >> 4, h = bh & 15;
  const u16* src = C1 + (size_t)(b * 2048 + s0) * 6144 + 4096 + h * 128 + d0;
#pragma unroll
  for (int it = 0; it < 2; ++it) {
    int ss = it * 32 + (t >> 3);
    int dd = (t & 7) * 8;
    uint4 v = *(const uint4*)(src + (size_t)ss * 6144 + dd);
    *(uint4*)&tile[ss][dd] = v;
  }
  __syncthreads();
#pragma unroll
  for (int it = 0; it < 2; ++it) {
    int dd = it * 32 + (t >> 3);
    int ss0 = (t & 7) * 8;
    union { u16 q[8]; uint4 v; } u;
#pragma unroll
    for (int i = 0; i < 8; ++i) u.q[i] = tile[ss0 + i][dd];
    *(uint4*)(VT + (size_t)(bh * 128 + d0 + dd) * 2048 + s0 + ss0) = u.v;
  }
}

// ===================== GEMM: C[M][N] = A[M][2048] @ Bt[N][2048]^T =====================
template <int MODE>
__global__ __launch_bounds__(256, 2) void gemm_bt(const u16* __restrict__ A,
                                                  const u16* __restrict__ Bt,
                                                  void* __restrict__ Cout) {
  const int K = 2048;
  __shared__ u16 lds[2][2][8192];  // [dbuf][A,B][128*64]
  int tid = threadIdx.x;
  int lane = tid & 63;
  int c = lane & 15, g = lane >> 4;
  int wid = tid >> 6;
  int wr = wid >> 1, wc = wid & 1;
  size_t m0 = (size_t)blockIdx.y * 128;
  size_t n0 = (size_t)blockIdx.x * 128;
  const u16* Asrc = A + m0 * K;
  const u16* Bsrc = Bt + n0 * K;

  f32x4 acc[4][4];
#pragma unroll
  for (int i = 0; i < 4; ++i)
#pragma unroll
    for (int j = 0; j < 4; ++j) acc[i][j] = f32x4{0.f, 0.f, 0.f, 0.f};

  auto stage = [&](int buf, int kt) {
#pragma unroll
    for (int i = 0; i < 4; ++i) {
      int p = i * 4096 + tid * 16;
      int row = p >> 7;
      int inner = (p & 127) ^ ((row & 7) << 4);
      int col = (kt * 128 + inner) >> 1;
      __builtin_amdgcn_global_load_lds((glb32_t*)(Asrc + (size_t)row * K + col),
                                       (lds32_t*)(&lds[buf][0][p >> 1]), 16, 0, 0);
      __builtin_amdgcn_global_load_lds((glb32_t*)(Bsrc + (size_t)row * K + col),
                                       (lds32_t*)(&lds[buf][1][p >> 1]), 16, 0, 0);
    }
  };

  stage(0, 0);
  asm volatile("s_waitcnt vmcnt(0)" ::: "memory");
  __syncthreads();
  int cur = 0;
  for (int kt = 0; kt < 32; ++kt) {
    if (kt + 1 < 32) stage(cur ^ 1, kt + 1);
    const u16* Ab = &lds[cur][0][0];
    const u16* Bb = &lds[cur][1][0];
#pragma unroll
    for (int kk = 0; kk < 2; ++kk) {
      bf16x8 af[4], bfr[4];
#pragma unroll
      for (int i = 0; i < 4; ++i) {
        int rowA = wr * 64 + i * 16 + c;
        int offA = rowA * 128 + ((kk * 64 + g * 16) ^ ((rowA & 7) << 4));
        af[i] = *(const bf16x8*)(Ab + (offA >> 1));
        int rowB = wc * 64 + i * 16 + c;
        int offB = rowB * 128 + ((kk * 64 + g * 16) ^ ((rowB & 7) << 4));
        bfr[i] = *(const bf16x8*)(Bb + (offB >> 1));
      }
#pragma unroll
      for (int i = 0; i < 4; ++i)
#pragma unroll
        for (int j = 0; j < 4; ++j) acc[i][j] = mfma16(af[i], bfr[j], acc[i][j]);
    }
    __syncthreads();
    cur ^= 1;
  }

  if (MODE == 0) {
    u16* C = (u16*)Cout;
#pragma unroll
    for (int i = 0; i < 4; ++i)
#pragma unroll
      for (int j = 0; j < 4; ++j) {
        size_t row = m0 + wr * 64 + i * 16 + g * 4;
        size_t col = n0 + wc * 64 + j * 16 + c;
#pragma unroll
        for (int r = 0; r < 4; ++r) C[(row + r) * 6144 + col] = f2bf(acc[i][j][r]);
      }
  } else {
    float* Y = (float*)Cout;
#pragma unroll
    for (int i = 0; i < 4; ++i)
#pragma unroll
      for (int j = 0; j < 4; ++j) {
        size_t row = m0 + wr * 64 + i * 16 + g * 4;
        int col = (int)(n0 + wc * 64 + j * 16 + c);
        float* base = (col < 1024) ? (Y + col) : (Y + 4194304 + (col - 1024));
#pragma unroll
        for (int r = 0; r < 4; ++r) base[(row + r) * 1024] = acc[i][j][r];
      }
  }
}

// ===================== Flash attention v5 =====================
// 8 waves/block (128 q-rows), KVBLK=64, dbuf LDS. Swapped QK^T; per-lane softmax
// with deferred cross-lane max + deferred lrun. P redistribution via
// permlane32_swap + permlane16_swap (register<->lane transposes, T12):
//   source lane (c,g): d[2m+b] = P[q=c][kv=16m+4g+2b..+1]
//   target lane (c,g): pa[half].dw[2J+b] = P[q=c][kv=32half+8g+4J+2b..+1]
// In (u,v)=(g&1,g>>1) coords the permutation is cyclic (m'->v, v->u, u->J);
// permlane32_swap = (reg,v)-transpose, permlane16_swap = (reg,u)-transpose.
__global__ __launch_bounds__(512) void attn_fwd(const u16* __restrict__ C1,
                                                const u16* __restrict__ VT,
                                                u16* __restrict__ O) {
  __shared__ u16 Kl[2][8192];   // [64 kv][128 d], XOR-swizzled 16B slots per row
  __shared__ u16 Vl[2][9216];   // [128 d][72], kv 0..63 + pad 8

  int tid = threadIdx.x;
  int lane = tid & 63;
  int w = tid >> 6;
  int c = lane & 15, g = lane >> 4;
  int qt = blockIdx.x;
  int bh = blockIdx.y;
  int b = bh >> 4, h = bh & 15;
  const size_t LDC = 6144;
  const u16* Qb = C1 + (size_t)(b * 2048 + qt * 128 + w * 16) * LDC + h * 128;
  const u16* Ks = C1 + (size_t)(b * 2048) * LDC + 2048 + h * 128;
  const u16* Vs = VT + (size_t)bh * 128 * 2048;

  bf16x8 qf[4];
#pragma unroll
  for (int kk = 0; kk < 4; ++kk)
    qf[kk] = *(const bf16x8*)(Qb + (size_t)c * LDC + kk * 32 + g * 8);

  float mrunS = -3e38f, lrun = 0.f;
  f32x4 o[8];
#pragma unroll
  for (int nt = 0; nt < 8; ++nt) o[nt] = f32x4{0.f, 0.f, 0.f, 0.f};

  const float SC = 0.125f * 1.44269504f;  // SCALE * log2(e)
  const int kr = tid >> 4, ksl = tid & 15;  // K staging: 32 rows x 16 slots / shot
  const int vd = tid >> 2, vs = tid & 3;    // V staging: 128 rows x 4 slots / shot

  // prologue: stage tile 0
#pragma unroll
  for (int i = 0; i < 2; ++i) {
    int row = i * 32 + kr;
    __builtin_amdgcn_global_load_lds(
        (glb32_t*)(Ks + (size_t)row * LDC + ((ksl ^ (kr & 15)) << 3)),
        (lds32_t*)&Kl[0][(i * 512 + tid) * 8], 16, 0, 0);
    uint4 vr = *(const uint4*)(Vs + (size_t)vd * 2048 + i * 32 + vs * 8);
    *(uint4*)&Vl[0][vd * 72 + i * 32 + vs * 8] = vr;
  }
  __syncthreads();

  int cur = 0;
  uint4 vreg[2];
  for (int t = 0; t < 32; ++t) {
    if (t < 31) {
      int kvn = (t + 1) * 64;
      vreg[0] = *(const uint4*)(Vs + (size_t)vd * 2048 + kvn + vs * 8);
      vreg[1] = *(const uint4*)(Vs + (size_t)vd * 2048 + kvn + 32 + vs * 8);
#pragma unroll
      for (int i = 0; i < 2; ++i) {
        int row = i * 32 + kr;
        __builtin_amdgcn_global_load_lds(
            (glb32_t*)(Ks + (size_t)(kvn + row) * LDC + ((ksl ^ (kr & 15)) << 3)),
            (lds32_t*)&Kl[cur ^ 1][(i * 512 + tid) * 8], 16, 0, 0);
      }
    }

    // ---- QK^T (swapped: S^T[kv][q]); lane holds kv = 16m+4g+r, q=c ----
    f32x4 s[4];
#pragma unroll
    for (int m = 0; m < 4; ++m) s[m] = f32x4{0.f, 0.f, 0.f, 0.f};
#pragma unroll
    for (int m = 0; m < 4; ++m)
#pragma unroll
      for (int kk = 0; kk < 4; ++kk) {
        bf16x8 kf = *(const bf16x8*)&Kl[cur][(16 * m + c) * 128 + (((4 * kk + g) ^ c) << 3)];
        s[m] = mfma16(kf, qf[kk], s[m]);
      }

    // ---- per-lane softmax over 16 kv values, deferred max + deferred lrun ----
    float mx01 = fmaxf(fmaxf(s[0][0], s[0][1]), fmaxf(s[0][2], s[0][3]));
    float mx23 = fmaxf(fmaxf(s[1][0], s[1][1]), fmaxf(s[1][2], s[1][3]));
    float mx45 = fmaxf(fmaxf(s[2][0], s[2][1]), fmaxf(s[2][2], s[2][3]));
    float mx67 = fmaxf(fmaxf(s[3][0], s[3][1]), fmaxf(s[3][2], s[3][3]));
    float mx = fmaxf(fmaxf(mx01, mx23), fmaxf(mx45, mx67));
    if (!__all(mx * SC <= mrunS + 8.0f)) {  // rare rescale
      mx = fmaxf(mx, __shfl_xor(mx, 16));
      mx = fmaxf(mx, __shfl_xor(mx, 32));
      float mn = fmaxf(mrunS, mx * SC);
      float al = exp2f(mrunS - mn);
      mrunS = mn;
      float alr[4];
#pragma unroll
      for (int r = 0; r < 4; ++r) alr[r] = __shfl(al, 4 * g + r);
#pragma unroll
      for (int nt = 0; nt < 8; ++nt)
#pragma unroll
        for (int r = 0; r < 4; ++r) o[nt][r] *= alr[r];
      lrun *= al;
    }
    float p[16];
#pragma unroll
    for (int m = 0; m < 4; ++m)
#pragma unroll
      for (int r = 0; r < 4; ++r) p[4 * m + r] = exp2f(fmaf(s[m][r], SC, -mrunS));
    float sA = (p[0] + p[1]) + (p[2] + p[3]);
    float sB = (p[4] + p[5]) + (p[6] + p[7]);
    float sC2 = (p[8] + p[9]) + (p[10] + p[11]);
    float sD = (p[12] + p[13]) + (p[14] + p[15]);
    lrun += (sA + sB) + (sC2 + sD);

    // ---- pack P to bf16 dwords: d[2m+b] = kv(16m+4g+2b, +1) ----
    u32 d[8];
#pragma unroll
    for (int m = 0; m < 4; ++m) {
      d[2 * m] = pk2(p[4 * m], p[4 * m + 1]);
      d[2 * m + 1] = pk2(p[4 * m + 2], p[4 * m + 3]);
    }

    // ---- P redistribution: permlane32_swap then permlane16_swap per (half,b) ----
    union { u32 dw[4]; bf16x8 v; } pa0, pa1;
#pragma unroll
    for (int b2 = 0; b2 < 2; ++b2) {
      u32 x0 = d[b2], x1 = d[2 + b2];
      asm("v_permlane32_swap_b32 %0, %1" : "+v"(x0), "+v"(x1));
      asm("v_permlane16_swap_b32 %0, %1" : "+v"(x0), "+v"(x1));
      pa0.dw[b2] = x0; pa0.dw[2 + b2] = x1;
      u32 y0 = d[4 + b2], y1 = d[6 + b2];
      asm("v_permlane32_swap_b32 %0, %1" : "+v"(y0), "+v"(y1));
      asm("v_permlane16_swap_b32 %0, %1" : "+v"(y0), "+v"(y1));
      pa1.dw[b2] = y0; pa1.dw[2 + b2] = y1;
    }

    // ---- PV: o[q=4g+r][d=nt*16+c] ----
#pragma unroll
    for (int nt = 0; nt < 8; ++nt) {
      bf16x8 vf0 = *(const bf16x8*)&Vl[cur][(nt * 16 + c) * 72 + g * 8];
      bf16x8 vf1 = *(const bf16x8*)&Vl[cur][(nt * 16 + c) * 72 + 32 + g * 8];
      o[nt] = mfma16(pa0.v, vf0, o[nt]);
      o[nt] = mfma16(pa1.v, vf1, o[nt]);
    }

    if (t < 31) {
      *(uint4*)&Vl[cur ^ 1][vd * 72 + vs * 8] = vreg[0];
      *(uint4*)&Vl[cur ^ 1][vd * 72 + 32 + vs * 8] = vreg[1];
    }
    __syncthreads();
    cur ^= 1;
  }

  // epilogue: finish deferred lrun reduction
  lrun += __shfl_xor(lrun, 16);
  lrun += __shfl_xor(lrun, 32);
  float inv = 1.0f / lrun;
  float invr[4];
#pragma unroll
  for (int r = 0; r < 4; ++r) invr[r] = __shfl(inv, 4 * g + r);
#pragma unroll
  for (int nt = 0; nt < 8; ++nt)
#pragma unroll
    for (int r = 0; r < 4; ++r) {
      size_t row = (size_t)(b * 2048 + qt * 128 + w * 16 + 4 * g + r);
      O[row * 2048 + h * 128 + nt * 16 + c] = f2bf(o[nt][r] * invr[r]);
    }
}

// ===================== launch =====================
extern "C" void kernel_launch(void* const* d_in, const int* in_sizes, int n_in,
                              void* d_out, int out_size, void* d_ws, size_t ws_size,
                              hipStream_t stream) {
  const float* zr   = (const float*)d_in[0];
  const float* zi   = (const float*)d_in[1];
  const float* wq_r = (const float*)d_in[2];
  const float* wq_i = (const float*)d_in[3];
  const float* wk_r = (const float*)d_in[4];
  const float* wk_i = (const float*)d_in[5];
  const float* wv_r = (const float*)d_in[6];
  const float* wv_i = (const float*)d_in[7];
  const float* wo_r = (const float*)d_in[8];
  const float* wo_i = (const float*)d_in[9];

  if (ws_size < (size_t)134217728) return;  // need 128 MiB scratch

  char* ws = (char*)d_ws;
  u16* X    = (u16*)(ws + 0);          //  16 MiB: [4096][2048]
  u16* Wqkv = (u16*)(ws + 16777216);   //  24 MiB: [6144][2048]
  u16* C1   = (u16*)(ws + 41943040);   //  48 MiB: [4096][6144] = [Q|K|V] head-interleaved
  u16* VT   = (u16*)(ws + 92274688);   //  16 MiB: [32][128][2048]
  u16* O    = (u16*)(ws + 109051904);  //  16 MiB: [4096][2048]
  u16* Wo   = (u16*)(ws + 125829120);  //   8 MiB: [2048][2048]

  pack_x<<<8192, 256, 0, stream>>>(zr, zi, X);
  pack_w<0><<<dim3(96, 32), 256, 0, stream>>>(wq_r, wq_i, wk_r, wk_i, wv_r, wv_i, Wqkv);
  pack_w<1><<<dim3(32, 32), 256, 0, stream>>>(wo_r, wo_i, wo_r, wo_i, wo_r, wo_i, Wo);
  gemm_bt<0><<<dim3(48, 32), 256, 0, stream>>>(X, Wqkv, C1);
  vtrans<<<dim3(32, 64), 256, 0, stream>>>(C1, VT);
  attn_fwd<<<dim3(16, 32), 512, 0, stream>>>(C1, VT, O);
  gemm_bt<1><<<dim3(16, 32), 256, 0, stream>>>(O, Wo, (float*)d_out);
}